// Round 1
// baseline (129.598 us; speedup 1.0000x reference)
//
#include <hip/hip_runtime.h>
#include <cstddef>
#include <cstdint>

#define D_MODEL 1024
#define D_STATE 16
#define D_INNER 2048
#define BATCH 2
#define SEQ 4096
#define NTOK (BATCH * SEQ)
#define EPS_LN 1e-5f

// ws layout (float offsets)
#define WS_PA 0                         // [16][1024]  P_A^T
#define WS_PB 16384                     // [16][1024]  P_B^T
#define WS_M 32768                      // [16][1024]  M^T
#define WS_CA 49152                     // [16] bias term for a
#define WS_CB 49168                     // [16] bias term for u
#define WS_A 49184                      // [B,S,16] decay gates
#define WS_U (49184 + 131072)           // [B,S,16] input drive
#define WS_S (49184 + 2 * 131072)       // [B,S,16] states
#define WS_CARRYA (49184 + 3 * 131072)  // [64 chunks][32 seq]
#define WS_CARRYU (WS_CARRYA + 2048)
#define WS_CARRYIN (WS_CARRYU + 2048)

// ---------------------------------------------------------------------------
// K1: precompute P_A = W_in^T @ A, P_B = W_in^T @ B_ssm, M = W_out @ C_ssm
//     (all stored transposed [n][1024]), plus cA = b_in@A, cB = b_in@B_ssm.
// grid: 192 matrix blocks (3 mats x 64 blocks of 16 d's) + 2 bias blocks.
// ---------------------------------------------------------------------------
__global__ __launch_bounds__(256) void precompute_kernel(
    const float* __restrict__ W_in, const float* __restrict__ b_in,
    const float* __restrict__ A, const float* __restrict__ Bs,
    const float* __restrict__ C, const float* __restrict__ W_out,
    float* __restrict__ ws) {
  __shared__ float red[256 * 16];
  const int bid = blockIdx.x;
  const int tid = threadIdx.x;
  float acc[16];
#pragma unroll
  for (int n = 0; n < 16; ++n) acc[n] = 0.f;

  if (bid < 192) {
    const int mat = bid >> 6;          // 0:P_A 1:P_B 2:M
    const int d0 = (bid & 63) * 16;    // 16 d's per block
    if (mat < 2) {
      const float* __restrict__ P = (mat == 0) ? A : Bs;
      const int dl = tid & 15;
      const int d = d0 + dl;
      for (int e = (tid >> 4); e < D_INNER; e += 16) {
        const float w = W_in[(size_t)e * D_MODEL + d];
        const float* pe = P + (size_t)e * 16;
#pragma unroll
        for (int n = 0; n < 16; ++n) acc[n] = fmaf(w, pe[n], acc[n]);
      }
    } else {
      const int dl = tid >> 4;
      const int d = d0 + dl;
      for (int e = (tid & 15); e < D_INNER; e += 16) {
        const float w = W_out[(size_t)d * D_INNER + e];
        const float* ce = C + (size_t)e * 16;
#pragma unroll
        for (int n = 0; n < 16; ++n) acc[n] = fmaf(w, ce[n], acc[n]);
      }
    }
#pragma unroll
    for (int n = 0; n < 16; ++n) red[tid * 16 + n] = acc[n];
    __syncthreads();

    if (mat < 2) {
      const int dl = tid & 15, n = tid >> 4;
      float s = 0.f;
#pragma unroll
      for (int k = 0; k < 16; ++k) s += red[(k * 16 + dl) * 16 + n];
      ws[(size_t)mat * 16384 + n * 1024 + d0 + dl] = s;
    } else {
      const int dl = tid >> 4, n = tid & 15;
      float s = 0.f;
#pragma unroll
      for (int k = 0; k < 16; ++k) s += red[(dl * 16 + k) * 16 + n];
      ws[(size_t)2 * 16384 + n * 1024 + d0 + dl] = s;
    }
  } else {
    const int which = bid - 192;  // 0:cA 1:cB
    const float* __restrict__ P = (which == 0) ? A : Bs;
    for (int e = tid; e < D_INNER; e += 256) {
      const float w = b_in[e];
      const float* pe = P + (size_t)e * 16;
#pragma unroll
      for (int n = 0; n < 16; ++n) acc[n] = fmaf(w, pe[n], acc[n]);
    }
#pragma unroll
    for (int n = 0; n < 16; ++n) red[tid * 16 + n] = acc[n];
    __syncthreads();
    if (tid < 16) {
      float s = 0.f;
      for (int k = 0; k < 256; ++k) s += red[k * 16 + tid];
      ws[WS_CA + which * 16 + tid] = s;
    }
  }
}

// ---------------------------------------------------------------------------
// K2: per token: LayerNorm(x) then a = sigmoid(xn@P_A + cA), u = xn@P_B + cB.
// One wave per token, 4 waves/block. grid = NTOK/4.
// ---------------------------------------------------------------------------
__global__ __launch_bounds__(256) void token_kernel(
    const float* __restrict__ x, const float* __restrict__ nw,
    const float* __restrict__ nb, const float* __restrict__ ws,
    float* __restrict__ a_buf, float* __restrict__ u_buf) {
  const int lane = threadIdx.x & 63;
  const int token = blockIdx.x * 4 + (threadIdx.x >> 6);
  const float4* __restrict__ xr =
      reinterpret_cast<const float4*>(x) + (size_t)token * 256;
  const float4* __restrict__ nw4 = reinterpret_cast<const float4*>(nw);
  const float4* __restrict__ nb4 = reinterpret_cast<const float4*>(nb);
  const float4* __restrict__ PA4 = reinterpret_cast<const float4*>(ws + WS_PA);
  const float4* __restrict__ PB4 = reinterpret_cast<const float4*>(ws + WS_PB);

  float4 xv[4];
  float sum = 0.f, sumsq = 0.f;
#pragma unroll
  for (int k = 0; k < 4; ++k) {
    xv[k] = xr[k * 64 + lane];
    sum += xv[k].x + xv[k].y + xv[k].z + xv[k].w;
    sumsq = fmaf(xv[k].x, xv[k].x, sumsq);
    sumsq = fmaf(xv[k].y, xv[k].y, sumsq);
    sumsq = fmaf(xv[k].z, xv[k].z, sumsq);
    sumsq = fmaf(xv[k].w, xv[k].w, sumsq);
  }
#pragma unroll
  for (int off = 32; off; off >>= 1) {
    sum += __shfl_xor(sum, off);
    sumsq += __shfl_xor(sumsq, off);
  }
  const float mu = sum * (1.0f / 1024.0f);
  const float var = fmaf(-mu, mu, sumsq * (1.0f / 1024.0f));
  const float rstd = rsqrtf(var + EPS_LN);

  float accA[16], accB[16];
#pragma unroll
  for (int n = 0; n < 16; ++n) {
    accA[n] = 0.f;
    accB[n] = 0.f;
  }

#pragma unroll
  for (int k = 0; k < 4; ++k) {
    const int idx = k * 64 + lane;
    const float4 w4 = nw4[idx];
    const float4 b4 = nb4[idx];
    const float xn0 = fmaf((xv[k].x - mu) * rstd, w4.x, b4.x);
    const float xn1 = fmaf((xv[k].y - mu) * rstd, w4.y, b4.y);
    const float xn2 = fmaf((xv[k].z - mu) * rstd, w4.z, b4.z);
    const float xn3 = fmaf((xv[k].w - mu) * rstd, w4.w, b4.w);
#pragma unroll
    for (int n = 0; n < 16; ++n) {
      const float4 pa = PA4[n * 256 + idx];
      const float4 pb = PB4[n * 256 + idx];
      accA[n] = fmaf(xn0, pa.x, accA[n]);
      accA[n] = fmaf(xn1, pa.y, accA[n]);
      accA[n] = fmaf(xn2, pa.z, accA[n]);
      accA[n] = fmaf(xn3, pa.w, accA[n]);
      accB[n] = fmaf(xn0, pb.x, accB[n]);
      accB[n] = fmaf(xn1, pb.y, accB[n]);
      accB[n] = fmaf(xn2, pb.z, accB[n]);
      accB[n] = fmaf(xn3, pb.w, accB[n]);
    }
  }
#pragma unroll
  for (int n = 0; n < 16; ++n) {
#pragma unroll
    for (int off = 32; off; off >>= 1) {
      accA[n] += __shfl_xor(accA[n], off);
      accB[n] += __shfl_xor(accB[n], off);
    }
  }
  if (lane == 0) {
    const float* __restrict__ cA = ws + WS_CA;
    const float* __restrict__ cB = ws + WS_CB;
    float* __restrict__ ar = a_buf + (size_t)token * 16;
    float* __restrict__ ur = u_buf + (size_t)token * 16;
#pragma unroll
    for (int n = 0; n < 16; ++n) {
      const float za = accA[n] + cA[n];
      ar[n] = 1.0f / (1.0f + __expf(-za));
      ur[n] = accB[n] + cB[n];
    }
  }
}

// ---------------------------------------------------------------------------
// K3: 3-phase chunked scan. 32 sequences (b,n), 64 chunks of 64 steps.
// Task index = chunk*32 + seq (seq minor -> coalesced).
// ---------------------------------------------------------------------------
__global__ __launch_bounds__(256) void scan1_kernel(
    const float* __restrict__ a_buf, const float* __restrict__ u_buf,
    float* __restrict__ carryA, float* __restrict__ carryU) {
  const int task = blockIdx.x * 256 + threadIdx.x;  // 0..2047
  const int seq = task & 31;
  const int chunk = task >> 5;
  const int b = seq >> 4, n = seq & 15;
  const size_t base = ((size_t)b * SEQ + (size_t)chunk * 64) * 16 + n;
  float Ap = 1.f, U = 0.f;
#pragma unroll 4
  for (int i = 0; i < 64; ++i) {
    const float av = a_buf[base + (size_t)i * 16];
    const float uv = u_buf[base + (size_t)i * 16];
    U = fmaf(U, av, uv);
    Ap *= av;
  }
  carryA[task] = Ap;
  carryU[task] = U;
}

__global__ __launch_bounds__(64) void scan2_kernel(
    const float* __restrict__ carryA, const float* __restrict__ carryU,
    float* __restrict__ carryin) {
  const int seq = threadIdx.x;
  if (seq >= 32) return;
  float c = 0.f;
  for (int ch = 0; ch < 64; ++ch) {
    carryin[ch * 32 + seq] = c;
    c = fmaf(c, carryA[ch * 32 + seq], carryU[ch * 32 + seq]);
  }
}

__global__ __launch_bounds__(256) void scan3_kernel(
    const float* __restrict__ a_buf, const float* __restrict__ u_buf,
    const float* __restrict__ carryin, float* __restrict__ states) {
  const int task = blockIdx.x * 256 + threadIdx.x;
  const int seq = task & 31;
  const int chunk = task >> 5;
  const int b = seq >> 4, n = seq & 15;
  const size_t base = ((size_t)b * SEQ + (size_t)chunk * 64) * 16 + n;
  float s = carryin[task];
#pragma unroll 4
  for (int i = 0; i < 64; ++i) {
    const float av = a_buf[base + (size_t)i * 16];
    const float uv = u_buf[base + (size_t)i * 16];
    s = fmaf(s, av, uv);
    states[base + (size_t)i * 16] = s;
  }
}

// ---------------------------------------------------------------------------
// K4: out = states @ M^T + b_out + x. One block per token.
// ---------------------------------------------------------------------------
__global__ __launch_bounds__(256) void out_kernel(
    const float* __restrict__ x, const float* __restrict__ states,
    const float* __restrict__ Mt, const float* __restrict__ b_out,
    float* __restrict__ out) {
  const int token = blockIdx.x;
  const int tid = threadIdx.x;
  __shared__ float sst[16];
  if (tid < 16) sst[tid] = states[(size_t)token * 16 + tid];
  __syncthreads();
  const float4* __restrict__ x4 =
      reinterpret_cast<const float4*>(x) + (size_t)token * 256;
  const float4* __restrict__ bo4 = reinterpret_cast<const float4*>(b_out);
  const float4* __restrict__ M4 = reinterpret_cast<const float4*>(Mt);
  const float4 xv = x4[tid];
  const float4 bv = bo4[tid];
  float r0 = xv.x + bv.x;
  float r1 = xv.y + bv.y;
  float r2 = xv.z + bv.z;
  float r3 = xv.w + bv.w;
#pragma unroll
  for (int n = 0; n < 16; ++n) {
    const float s = sst[n];
    const float4 m = M4[n * 256 + tid];
    r0 = fmaf(s, m.x, r0);
    r1 = fmaf(s, m.y, r1);
    r2 = fmaf(s, m.z, r2);
    r3 = fmaf(s, m.w, r3);
  }
  float4 o;
  o.x = r0;
  o.y = r1;
  o.z = r2;
  o.w = r3;
  reinterpret_cast<float4*>(out)[(size_t)token * 256 + tid] = o;
}

// ---------------------------------------------------------------------------
extern "C" void kernel_launch(void* const* d_in, const int* in_sizes, int n_in,
                              void* d_out, int out_size, void* d_ws,
                              size_t ws_size, hipStream_t stream) {
  const float* x = (const float*)d_in[0];
  const float* norm_w = (const float*)d_in[1];
  const float* norm_b = (const float*)d_in[2];
  const float* W_in = (const float*)d_in[3];
  const float* b_in = (const float*)d_in[4];
  const float* A = (const float*)d_in[5];
  const float* B_ssm = (const float*)d_in[6];
  const float* C_ssm = (const float*)d_in[7];
  const float* W_out = (const float*)d_in[8];
  const float* b_out = (const float*)d_in[9];
  float* ws = (float*)d_ws;
  float* out = (float*)d_out;

  precompute_kernel<<<194, 256, 0, stream>>>(W_in, b_in, A, B_ssm, C_ssm,
                                             W_out, ws);
  token_kernel<<<NTOK / 4, 256, 0, stream>>>(x, norm_w, norm_b, ws, ws + WS_A,
                                             ws + WS_U);
  scan1_kernel<<<8, 256, 0, stream>>>(ws + WS_A, ws + WS_U, ws + WS_CARRYA,
                                      ws + WS_CARRYU);
  scan2_kernel<<<1, 64, 0, stream>>>(ws + WS_CARRYA, ws + WS_CARRYU,
                                     ws + WS_CARRYIN);
  scan3_kernel<<<8, 256, 0, stream>>>(ws + WS_A, ws + WS_U, ws + WS_CARRYIN,
                                      ws + WS_S);
  out_kernel<<<NTOK, 256, 0, stream>>>(x, ws + WS_S, ws + WS_M, b_out, out);
}

// Round 2
// 104.557 us; speedup vs baseline: 1.2395x; 1.2395x over previous
//
#include <hip/hip_runtime.h>
#include <cstddef>
#include <cstdint>

#define D_MODEL 1024
#define D_STATE 16
#define D_INNER 2048
#define BATCH 2
#define SEQ 4096
#define NTOK (BATCH * SEQ)
#define EPS_LN 1e-5f

// ws float offsets
#define WS_PA 0          // [16][1024] PA'' = norm_w ⊙ (W_in^T A)
#define WS_PB 16384      // [16][1024] PB'' = norm_w ⊙ (W_in^T B)
#define WS_M 32768       // [16][1024] M^T, M = W_out @ C
#define WS_CA 49152      // [16] c'A = b_in@A + norm_b·PAT_A
#define WS_CB 49168      // [16] c'B
#define WS_TA 49184      // [16] T_A[n] = sum_d PA''[n][d]
#define WS_TB 49200      // [16]
#define WS_A 49216                  // [NTOK][16] decay gates
#define WS_U (WS_A + NTOK * 16)     // [NTOK][16] input drive
#define WS_S (WS_U + NTOK * 16)     // [NTOK][16] states
#define WS_CARRYA (WS_S + NTOK * 16)
#define WS_CARRYU (WS_CARRYA + 2048)
#define WS_CARRYIN (WS_CARRYU + 2048)
#define WS_PART WS_A  // [16 ech][1024 d][32] partials (2MB), dead before WS_A used

// ---------------------------------------------------------------------------
// K1: partials for PA/PB (blocks 0..127), M^T direct (blocks 128..191),
//     bias cA/cB (blocks 192,193).
// ---------------------------------------------------------------------------
__global__ __launch_bounds__(256) void precompute_kernel(
    const float* __restrict__ W_in, const float* __restrict__ b_in,
    const float* __restrict__ A, const float* __restrict__ Bs,
    const float* __restrict__ C, const float* __restrict__ W_out,
    float* __restrict__ ws) {
  __shared__ float red[256 * 16];  // 16 KB scratch (PAB combine / bias reduce)
  const int bid = blockIdx.x;
  const int tid = threadIdx.x;

  if (bid < 128) {
    // ---- PA/PB partials: dblk = bid>>4 (8 x 128 d), ech = bid&15 (16 x 128 e)
    const int dblk = bid >> 4;
    const int ech = bid & 15;
    const int dl = tid & 127;
    const int ep = tid >> 7;  // e-half
    const int d = dblk * 128 + dl;
    const int e0 = ech * 128 + ep * 64;
    const float4* A4 = reinterpret_cast<const float4*>(A);
    const float4* B4 = reinterpret_cast<const float4*>(Bs);
    float accA[16], accB[16];
#pragma unroll
    for (int n = 0; n < 16; ++n) {
      accA[n] = 0.f;
      accB[n] = 0.f;
    }
    for (int e = e0; e < e0 + 64; ++e) {
      const float w = W_in[(size_t)e * D_MODEL + d];
#pragma unroll
      for (int q = 0; q < 4; ++q) {
        const float4 av = A4[(size_t)e * 4 + q];
        const float4 bv = B4[(size_t)e * 4 + q];
        accA[q * 4 + 0] = fmaf(w, av.x, accA[q * 4 + 0]);
        accA[q * 4 + 1] = fmaf(w, av.y, accA[q * 4 + 1]);
        accA[q * 4 + 2] = fmaf(w, av.z, accA[q * 4 + 2]);
        accA[q * 4 + 3] = fmaf(w, av.w, accA[q * 4 + 3]);
        accB[q * 4 + 0] = fmaf(w, bv.x, accB[q * 4 + 0]);
        accB[q * 4 + 1] = fmaf(w, bv.y, accB[q * 4 + 1]);
        accB[q * 4 + 2] = fmaf(w, bv.z, accB[q * 4 + 2]);
        accB[q * 4 + 3] = fmaf(w, bv.w, accB[q * 4 + 3]);
      }
    }
    if (ep) {
#pragma unroll
      for (int n = 0; n < 16; ++n) {
        red[dl * 32 + n] = accA[n];
        red[dl * 32 + 16 + n] = accB[n];
      }
    }
    __syncthreads();
    if (!ep) {
      float* part = ws + WS_PART + ((size_t)ech * 1024 + d) * 32;
#pragma unroll
      for (int n = 0; n < 16; ++n) {
        part[n] = accA[n] + red[dl * 32 + n];
        part[16 + n] = accB[n] + red[dl * 32 + 16 + n];
      }
    }
  } else if (bid < 192) {
    // ---- M^T: wave handles 4 d-rows over full e
    const int lane = tid & 63;
    const int wid = ((bid - 128) << 2) + (tid >> 6);  // 0..255
    const int dbase = wid * 4;
    const float4* W4 = reinterpret_cast<const float4*>(W_out);
    const float4* C4 = reinterpret_cast<const float4*>(C);
    float v[64];  // v[rr*16+n]
#pragma unroll
    for (int i = 0; i < 64; ++i) v[i] = 0.f;
    for (int i = 0; i < 8; ++i) {
      const int eb = i * 256 + lane * 4;
      float4 c4[4][4];
#pragma unroll
      for (int j = 0; j < 4; ++j)
#pragma unroll
        for (int q = 0; q < 4; ++q) c4[j][q] = C4[(size_t)(eb + j) * 4 + q];
#pragma unroll
      for (int rr = 0; rr < 4; ++rr) {
        const float4 w4 = W4[(size_t)(dbase + rr) * 512 + i * 64 + lane];
        float wj[4] = {w4.x, w4.y, w4.z, w4.w};
#pragma unroll
        for (int j = 0; j < 4; ++j) {
#pragma unroll
          for (int q = 0; q < 4; ++q) {
            const float4 cv = c4[j][q];
            v[rr * 16 + q * 4 + 0] = fmaf(wj[j], cv.x, v[rr * 16 + q * 4 + 0]);
            v[rr * 16 + q * 4 + 1] = fmaf(wj[j], cv.y, v[rr * 16 + q * 4 + 1]);
            v[rr * 16 + q * 4 + 2] = fmaf(wj[j], cv.z, v[rr * 16 + q * 4 + 2]);
            v[rr * 16 + q * 4 + 3] = fmaf(wj[j], cv.w, v[rr * 16 + q * 4 + 3]);
          }
        }
      }
    }
    // fold-reduce: lane L ends holding full sum of v[L]
#pragma unroll
    for (int off = 32; off >= 1; off >>= 1) {
      const bool sel = (lane & off) != 0;
#pragma unroll
      for (int i = 0; i < 64; ++i) {
        if (i < off) {
          const float keep = sel ? v[i + off] : v[i];
          const float send = sel ? v[i] : v[i + off];
          v[i] = keep + __shfl_xor(send, off);
        }
      }
    }
    const int rr = lane >> 4;
    const int n = lane & 15;
    ws[WS_M + (size_t)n * 1024 + dbase + rr] = v[0];
  } else {
    // ---- bias: cA (bid 192), cB (bid 193)
    const int which = bid - 192;
    const float* __restrict__ P = (which == 0) ? A : Bs;
    float acc[16];
#pragma unroll
    for (int n = 0; n < 16; ++n) acc[n] = 0.f;
    for (int e = tid; e < D_INNER; e += 256) {
      const float w = b_in[e];
      const float* pe = P + (size_t)e * 16;
#pragma unroll
      for (int n = 0; n < 16; ++n) acc[n] = fmaf(w, pe[n], acc[n]);
    }
#pragma unroll
    for (int n = 0; n < 16; ++n) red[tid * 16 + n] = acc[n];
    __syncthreads();
    if (tid < 16) {
      float s = 0.f;
      for (int k = 0; k < 256; ++k) s += red[k * 16 + tid];
      ws[WS_CA + which * 16 + tid] = s;
    }
  }
}

// ---------------------------------------------------------------------------
// K2: reduce partials -> PA''/PB'' (w-folded), T constants, c' = c + nb·PAT.
// blocks 0..127: finals; blocks 128..159: T/c' per output c.
// ---------------------------------------------------------------------------
__global__ __launch_bounds__(256) void reduce_kernel(
    const float* __restrict__ nw, const float* __restrict__ nb,
    float* __restrict__ ws) {
  const int bid = blockIdx.x;
  const int tid = threadIdx.x;
  if (bid < 128) {
    const int o = bid * 256 + tid;  // 0..32767 = d*32 + c
    const int d = o >> 5;
    const int c = o & 31;
    float s = 0.f;
#pragma unroll
    for (int ch = 0; ch < 16; ++ch) s += ws[WS_PART + (size_t)ch * 32768 + o];
    const float vfin = s * nw[d];
    if (c < 16)
      ws[WS_PA + (size_t)c * 1024 + d] = vfin;
    else
      ws[WS_PB + (size_t)(c - 16) * 1024 + d] = vfin;
  } else {
    const int c = bid - 128;  // 0..31
    float tAcc = 0.f, uAcc = 0.f;
    for (int d = tid; d < 1024; d += 256) {
      float p = 0.f;
#pragma unroll
      for (int ch = 0; ch < 16; ++ch)
        p += ws[WS_PART + (size_t)ch * 32768 + d * 32 + c];
      tAcc = fmaf(nw[d], p, tAcc);
      uAcc = fmaf(nb[d], p, uAcc);
    }
#pragma unroll
    for (int off = 32; off; off >>= 1) {
      tAcc += __shfl_xor(tAcc, off);
      uAcc += __shfl_xor(uAcc, off);
    }
    __shared__ float rT[4], rU[4];
    const int wv = tid >> 6;
    if ((tid & 63) == 0) {
      rT[wv] = tAcc;
      rU[wv] = uAcc;
    }
    __syncthreads();
    if (tid == 0) {
      ws[WS_TA + c] = rT[0] + rT[1] + rT[2] + rT[3];
      ws[WS_CA + c] += rU[0] + rU[1] + rU[2] + rU[3];
    }
  }
}

// ---------------------------------------------------------------------------
// K3: token kernel. logitA = rstd*(x·PA'' - mu*T_A) + c'A (single raw-x pass).
// Lane split: g = lane>>4 owns d-16th-slice, np = lane&15 owns output n.
// 8 tokens per wave amortize LDS reads. 4 d-quarters staged (33 KB LDS).
// ---------------------------------------------------------------------------
__global__ __launch_bounds__(256) void token_kernel(
    const float* __restrict__ x, const float* __restrict__ ws,
    float* __restrict__ a_buf, float* __restrict__ u_buf) {
  __shared__ float4 lds4[32 * 65];  // 32 rows (PA 0..15, PB 16..31), pad 65
  const int tid = threadIdx.x;
  const int lane = tid & 63;
  const int wv = tid >> 6;
  const int g = lane >> 4;
  const int np = lane & 15;
  const int t0 = blockIdx.x * 32 + wv * 8;

  const float4* __restrict__ x4 = reinterpret_cast<const float4*>(x);
  const float4* __restrict__ ws4 = reinterpret_cast<const float4*>(ws);

  float sum[8], sq[8], SA[8], SB[8];
#pragma unroll
  for (int t = 0; t < 8; ++t) {
    sum[t] = 0.f;
    sq[t] = 0.f;
    SA[t] = 0.f;
    SB[t] = 0.f;
  }

  for (int p = 0; p < 4; ++p) {
    __syncthreads();
#pragma unroll
    for (int i = 0; i < 8; ++i) {
      const int idx = i * 256 + tid;  // 0..2047
      const int r = idx >> 6;
      const int u = idx & 63;
      lds4[r * 65 + u] = ws4[(size_t)r * 256 + p * 64 + u];
    }
    __syncthreads();
    // stats partial (coalesced)
#pragma unroll
    for (int t = 0; t < 8; ++t) {
      const float4 xs = x4[(size_t)(t0 + t) * 256 + p * 64 + lane];
      sum[t] += xs.x + xs.y + xs.z + xs.w;
      sq[t] = fmaf(xs.x, xs.x, sq[t]);
      sq[t] = fmaf(xs.y, xs.y, sq[t]);
      sq[t] = fmaf(xs.z, xs.z, sq[t]);
      sq[t] = fmaf(xs.w, xs.w, sq[t]);
    }
    // projections
#pragma unroll
    for (int j = 0; j < 16; ++j) {
      const float4 pa = lds4[np * 65 + g * 16 + j];
      const float4 pb = lds4[(16 + np) * 65 + g * 16 + j];
#pragma unroll
      for (int t = 0; t < 8; ++t) {
        const float4 xb = x4[(size_t)(t0 + t) * 256 + p * 64 + g * 16 + j];
        SA[t] = fmaf(xb.x, pa.x, SA[t]);
        SA[t] = fmaf(xb.y, pa.y, SA[t]);
        SA[t] = fmaf(xb.z, pa.z, SA[t]);
        SA[t] = fmaf(xb.w, pa.w, SA[t]);
        SB[t] = fmaf(xb.x, pb.x, SB[t]);
        SB[t] = fmaf(xb.y, pb.y, SB[t]);
        SB[t] = fmaf(xb.z, pb.z, SB[t]);
        SB[t] = fmaf(xb.w, pb.w, SB[t]);
      }
    }
  }
  // finish
#pragma unroll
  for (int t = 0; t < 8; ++t) {
    float s = sum[t], q = sq[t];
#pragma unroll
    for (int off = 32; off; off >>= 1) {
      s += __shfl_xor(s, off);
      q += __shfl_xor(q, off);
    }
    const float mu = s * (1.0f / 1024.0f);
    const float var = fmaf(-mu, mu, q * (1.0f / 1024.0f));
    const float rstd = rsqrtf(var + EPS_LN);
    float sa = SA[t] + __shfl_xor(SA[t], 16);
    sa += __shfl_xor(sa, 32);
    float sb = SB[t] + __shfl_xor(SB[t], 16);
    sb += __shfl_xor(sb, 32);
    if (g == 0) {
      const float TA = ws[WS_TA + np];
      const float TB = ws[WS_TB + np];
      const float cA = ws[WS_CA + np];
      const float cB = ws[WS_CB + np];
      const float zA = fmaf(rstd, fmaf(-mu, TA, sa), cA);
      const float zB = fmaf(rstd, fmaf(-mu, TB, sb), cB);
      a_buf[(size_t)(t0 + t) * 16 + np] = 1.0f / (1.0f + __expf(-zA));
      u_buf[(size_t)(t0 + t) * 16 + np] = zB;
    }
  }
}

// ---------------------------------------------------------------------------
// K4-6: 3-phase chunked scan (32 sequences, 64 chunks x 64 steps).
// ---------------------------------------------------------------------------
__global__ __launch_bounds__(256) void scan1_kernel(
    const float* __restrict__ a_buf, const float* __restrict__ u_buf,
    float* __restrict__ carryA, float* __restrict__ carryU) {
  const int task = blockIdx.x * 256 + threadIdx.x;  // 0..2047
  const int seq = task & 31;
  const int chunk = task >> 5;
  const int b = seq >> 4, n = seq & 15;
  const size_t base = ((size_t)b * SEQ + (size_t)chunk * 64) * 16 + n;
  float Ap = 1.f, U = 0.f;
#pragma unroll 8
  for (int i = 0; i < 64; ++i) {
    const float av = a_buf[base + (size_t)i * 16];
    const float uv = u_buf[base + (size_t)i * 16];
    U = fmaf(U, av, uv);
    Ap *= av;
  }
  carryA[task] = Ap;
  carryU[task] = U;
}

__global__ __launch_bounds__(64) void scan2_kernel(
    const float* __restrict__ carryA, const float* __restrict__ carryU,
    float* __restrict__ carryin) {
  const int seq = threadIdx.x;
  if (seq >= 32) return;
  float c = 0.f;
  for (int ch = 0; ch < 64; ++ch) {
    carryin[ch * 32 + seq] = c;
    c = fmaf(c, carryA[ch * 32 + seq], carryU[ch * 32 + seq]);
  }
}

__global__ __launch_bounds__(256) void scan3_kernel(
    const float* __restrict__ a_buf, const float* __restrict__ u_buf,
    const float* __restrict__ carryin, float* __restrict__ states) {
  const int task = blockIdx.x * 256 + threadIdx.x;
  const int seq = task & 31;
  const int chunk = task >> 5;
  const int b = seq >> 4, n = seq & 15;
  const size_t base = ((size_t)b * SEQ + (size_t)chunk * 64) * 16 + n;
  float s = carryin[task];
#pragma unroll 8
  for (int i = 0; i < 64; ++i) {
    const float av = a_buf[base + (size_t)i * 16];
    const float uv = u_buf[base + (size_t)i * 16];
    s = fmaf(s, av, uv);
    states[base + (size_t)i * 16] = s;
  }
}

// ---------------------------------------------------------------------------
// K7: out = states @ M^T + b_out + x. 4 tokens per wave (M^T reads amortized).
// ---------------------------------------------------------------------------
__global__ __launch_bounds__(256) void out_kernel(
    const float* __restrict__ x, const float* __restrict__ ws,
    const float* __restrict__ b_out, float* __restrict__ out) {
  const int tid = threadIdx.x;
  const int lane = tid & 63;
  const int wv = tid >> 6;
  const int t0 = blockIdx.x * 16 + wv * 4;
  const float4* __restrict__ x4 = reinterpret_cast<const float4*>(x);
  const float4* __restrict__ M4 = reinterpret_cast<const float4*>(ws + WS_M);
  const float4* __restrict__ b4 = reinterpret_cast<const float4*>(b_out);
  const float* __restrict__ st = ws + WS_S;
  float4* __restrict__ o4 = reinterpret_cast<float4*>(out);

  float s[4][16];  // wave-uniform -> scalar regs
#pragma unroll
  for (int tt = 0; tt < 4; ++tt)
#pragma unroll
    for (int n = 0; n < 16; ++n) s[tt][n] = st[(size_t)(t0 + tt) * 16 + n];

#pragma unroll
  for (int k = 0; k < 4; ++k) {
    const float4 bv = b4[k * 64 + lane];
    float4 acc[4];
#pragma unroll
    for (int tt = 0; tt < 4; ++tt) {
      const float4 xv = x4[(size_t)(t0 + tt) * 256 + k * 64 + lane];
      acc[tt] =
          make_float4(xv.x + bv.x, xv.y + bv.y, xv.z + bv.z, xv.w + bv.w);
    }
#pragma unroll
    for (int n = 0; n < 16; ++n) {
      const float4 m = M4[(size_t)n * 256 + k * 64 + lane];
#pragma unroll
      for (int tt = 0; tt < 4; ++tt) {
        acc[tt].x = fmaf(s[tt][n], m.x, acc[tt].x);
        acc[tt].y = fmaf(s[tt][n], m.y, acc[tt].y);
        acc[tt].z = fmaf(s[tt][n], m.z, acc[tt].z);
        acc[tt].w = fmaf(s[tt][n], m.w, acc[tt].w);
      }
    }
#pragma unroll
    for (int tt = 0; tt < 4; ++tt)
      o4[(size_t)(t0 + tt) * 256 + k * 64 + lane] = acc[tt];
  }
}

// ---------------------------------------------------------------------------
extern "C" void kernel_launch(void* const* d_in, const int* in_sizes, int n_in,
                              void* d_out, int out_size, void* d_ws,
                              size_t ws_size, hipStream_t stream) {
  const float* x = (const float*)d_in[0];
  const float* norm_w = (const float*)d_in[1];
  const float* norm_b = (const float*)d_in[2];
  const float* W_in = (const float*)d_in[3];
  const float* b_in = (const float*)d_in[4];
  const float* A = (const float*)d_in[5];
  const float* B_ssm = (const float*)d_in[6];
  const float* C_ssm = (const float*)d_in[7];
  const float* W_out = (const float*)d_in[8];
  const float* b_out = (const float*)d_in[9];
  float* ws = (float*)d_ws;
  float* out = (float*)d_out;

  precompute_kernel<<<194, 256, 0, stream>>>(W_in, b_in, A, B_ssm, C_ssm,
                                             W_out, ws);
  reduce_kernel<<<160, 256, 0, stream>>>(norm_w, norm_b, ws);
  token_kernel<<<256, 256, 0, stream>>>(x, ws, ws + WS_A, ws + WS_U);
  scan1_kernel<<<8, 256, 0, stream>>>(ws + WS_A, ws + WS_U, ws + WS_CARRYA,
                                      ws + WS_CARRYU);
  scan2_kernel<<<1, 64, 0, stream>>>(ws + WS_CARRYA, ws + WS_CARRYU,
                                     ws + WS_CARRYIN);
  scan3_kernel<<<8, 256, 0, stream>>>(ws + WS_A, ws + WS_U, ws + WS_CARRYIN,
                                      ws + WS_S);
  out_kernel<<<512, 256, 0, stream>>>(x, ws, b_out, out);
}

// Round 3
// 103.257 us; speedup vs baseline: 1.2551x; 1.0126x over previous
//
#include <hip/hip_runtime.h>
#include <cstddef>
#include <cstdint>

#define D_MODEL 1024
#define D_STATE 16
#define D_INNER 2048
#define BATCH 2
#define SEQ 4096
#define NTOK (BATCH * SEQ)
#define EPS_LN 1e-5f

// ws float offsets
#define WS_PA 0          // [16][1024] PA'' = norm_w ⊙ (W_in^T A)
#define WS_PB 16384      // [16][1024] PB'' = norm_w ⊙ (W_in^T B)
#define WS_M 32768       // [16][1024] M^T, M = W_out @ C
#define WS_CA 49152      // [16] c'A = b_in@A + norm_b·PAT_A
#define WS_CB 49168      // [16] c'B
#define WS_TA 49184      // [16] T_A[n] = sum_d PA''[n][d]
#define WS_TB 49200      // [16]
#define WS_A 49216                  // [NTOK][16] decay gates
#define WS_U (WS_A + NTOK * 16)     // [NTOK][16] input drive
#define WS_S (WS_U + NTOK * 16)     // [NTOK][16] states
#define WS_CARRYA (WS_S + NTOK * 16)
#define WS_CARRYU (WS_CARRYA + 2048)
#define WS_CARRYIN (WS_CARRYU + 2048)
#define WS_PART WS_A  // [16 ech][1024 d][32] partials (2MB), dead before WS_A used

// ---------------------------------------------------------------------------
// K1: partials for PA/PB (blocks 0..127), M^T direct (blocks 128..191),
//     bias cA/cB (blocks 192,193).
// ---------------------------------------------------------------------------
__global__ __launch_bounds__(256) void precompute_kernel(
    const float* __restrict__ W_in, const float* __restrict__ b_in,
    const float* __restrict__ A, const float* __restrict__ Bs,
    const float* __restrict__ C, const float* __restrict__ W_out,
    float* __restrict__ ws) {
  __shared__ float red[256 * 16];  // 16 KB scratch (PAB combine / bias reduce)
  const int bid = blockIdx.x;
  const int tid = threadIdx.x;

  if (bid < 128) {
    // ---- PA/PB partials: dblk = bid>>4 (8 x 128 d), ech = bid&15 (16 x 128 e)
    const int dblk = bid >> 4;
    const int ech = bid & 15;
    const int dl = tid & 127;
    const int ep = tid >> 7;  // e-half
    const int d = dblk * 128 + dl;
    const int e0 = ech * 128 + ep * 64;
    const float4* A4 = reinterpret_cast<const float4*>(A);
    const float4* B4 = reinterpret_cast<const float4*>(Bs);
    float accA[16], accB[16];
#pragma unroll
    for (int n = 0; n < 16; ++n) {
      accA[n] = 0.f;
      accB[n] = 0.f;
    }
    for (int e = e0; e < e0 + 64; ++e) {
      const float w = W_in[(size_t)e * D_MODEL + d];
#pragma unroll
      for (int q = 0; q < 4; ++q) {
        const float4 av = A4[(size_t)e * 4 + q];
        const float4 bv = B4[(size_t)e * 4 + q];
        accA[q * 4 + 0] = fmaf(w, av.x, accA[q * 4 + 0]);
        accA[q * 4 + 1] = fmaf(w, av.y, accA[q * 4 + 1]);
        accA[q * 4 + 2] = fmaf(w, av.z, accA[q * 4 + 2]);
        accA[q * 4 + 3] = fmaf(w, av.w, accA[q * 4 + 3]);
        accB[q * 4 + 0] = fmaf(w, bv.x, accB[q * 4 + 0]);
        accB[q * 4 + 1] = fmaf(w, bv.y, accB[q * 4 + 1]);
        accB[q * 4 + 2] = fmaf(w, bv.z, accB[q * 4 + 2]);
        accB[q * 4 + 3] = fmaf(w, bv.w, accB[q * 4 + 3]);
      }
    }
    if (ep) {
#pragma unroll
      for (int n = 0; n < 16; ++n) {
        red[dl * 32 + n] = accA[n];
        red[dl * 32 + 16 + n] = accB[n];
      }
    }
    __syncthreads();
    if (!ep) {
      float* part = ws + WS_PART + ((size_t)ech * 1024 + d) * 32;
#pragma unroll
      for (int n = 0; n < 16; ++n) {
        part[n] = accA[n] + red[dl * 32 + n];
        part[16 + n] = accB[n] + red[dl * 32 + 16 + n];
      }
    }
  } else if (bid < 192) {
    // ---- M^T: wave handles 4 d-rows over full e
    const int lane = tid & 63;
    const int wid = ((bid - 128) << 2) + (tid >> 6);  // 0..255
    const int dbase = wid * 4;
    const float4* W4 = reinterpret_cast<const float4*>(W_out);
    const float4* C4 = reinterpret_cast<const float4*>(C);
    float v[64];  // v[rr*16+n]
#pragma unroll
    for (int i = 0; i < 64; ++i) v[i] = 0.f;
    for (int i = 0; i < 8; ++i) {
      const int eb = i * 256 + lane * 4;
      float4 c4[4][4];
#pragma unroll
      for (int j = 0; j < 4; ++j)
#pragma unroll
        for (int q = 0; q < 4; ++q) c4[j][q] = C4[(size_t)(eb + j) * 4 + q];
#pragma unroll
      for (int rr = 0; rr < 4; ++rr) {
        const float4 w4 = W4[(size_t)(dbase + rr) * 512 + i * 64 + lane];
        float wj[4] = {w4.x, w4.y, w4.z, w4.w};
#pragma unroll
        for (int j = 0; j < 4; ++j) {
#pragma unroll
          for (int q = 0; q < 4; ++q) {
            const float4 cv = c4[j][q];
            v[rr * 16 + q * 4 + 0] = fmaf(wj[j], cv.x, v[rr * 16 + q * 4 + 0]);
            v[rr * 16 + q * 4 + 1] = fmaf(wj[j], cv.y, v[rr * 16 + q * 4 + 1]);
            v[rr * 16 + q * 4 + 2] = fmaf(wj[j], cv.z, v[rr * 16 + q * 4 + 2]);
            v[rr * 16 + q * 4 + 3] = fmaf(wj[j], cv.w, v[rr * 16 + q * 4 + 3]);
          }
        }
      }
    }
    // fold-reduce: lane L ends holding full sum of v[L]
#pragma unroll
    for (int off = 32; off >= 1; off >>= 1) {
      const bool sel = (lane & off) != 0;
#pragma unroll
      for (int i = 0; i < 64; ++i) {
        if (i < off) {
          const float keep = sel ? v[i + off] : v[i];
          const float send = sel ? v[i] : v[i + off];
          v[i] = keep + __shfl_xor(send, off);
        }
      }
    }
    const int rr = lane >> 4;
    const int n = lane & 15;
    ws[WS_M + (size_t)n * 1024 + dbase + rr] = v[0];
  } else {
    // ---- bias: cA (bid 192), cB (bid 193)
    const int which = bid - 192;
    const float* __restrict__ P = (which == 0) ? A : Bs;
    float acc[16];
#pragma unroll
    for (int n = 0; n < 16; ++n) acc[n] = 0.f;
    for (int e = tid; e < D_INNER; e += 256) {
      const float w = b_in[e];
      const float* pe = P + (size_t)e * 16;
#pragma unroll
      for (int n = 0; n < 16; ++n) acc[n] = fmaf(w, pe[n], acc[n]);
    }
#pragma unroll
    for (int n = 0; n < 16; ++n) red[tid * 16 + n] = acc[n];
    __syncthreads();
    if (tid < 16) {
      float s = 0.f;
      for (int k = 0; k < 256; ++k) s += red[k * 16 + tid];
      ws[WS_CA + which * 16 + tid] = s;
    }
  }
}

// ---------------------------------------------------------------------------
// K2: reduce partials -> PA''/PB'' (w-folded), T constants, c' = c + nb·PAT.
// blocks 0..127: finals; blocks 128..159: T/c' per output c.
// ---------------------------------------------------------------------------
__global__ __launch_bounds__(256) void reduce_kernel(
    const float* __restrict__ nw, const float* __restrict__ nb,
    float* __restrict__ ws) {
  const int bid = blockIdx.x;
  const int tid = threadIdx.x;
  if (bid < 128) {
    const int o = bid * 256 + tid;  // 0..32767 = d*32 + c
    const int d = o >> 5;
    const int c = o & 31;
    float s = 0.f;
#pragma unroll
    for (int ch = 0; ch < 16; ++ch) s += ws[WS_PART + (size_t)ch * 32768 + o];
    const float vfin = s * nw[d];
    if (c < 16)
      ws[WS_PA + (size_t)c * 1024 + d] = vfin;
    else
      ws[WS_PB + (size_t)(c - 16) * 1024 + d] = vfin;
  } else {
    const int c = bid - 128;  // 0..31
    float tAcc = 0.f, uAcc = 0.f;
    for (int d = tid; d < 1024; d += 256) {
      float p = 0.f;
#pragma unroll
      for (int ch = 0; ch < 16; ++ch)
        p += ws[WS_PART + (size_t)ch * 32768 + d * 32 + c];
      tAcc = fmaf(nw[d], p, tAcc);
      uAcc = fmaf(nb[d], p, uAcc);
    }
#pragma unroll
    for (int off = 32; off; off >>= 1) {
      tAcc += __shfl_xor(tAcc, off);
      uAcc += __shfl_xor(uAcc, off);
    }
    __shared__ float rT[4], rU[4];
    const int wv = tid >> 6;
    if ((tid & 63) == 0) {
      rT[wv] = tAcc;
      rU[wv] = uAcc;
    }
    __syncthreads();
    if (tid == 0) {
      ws[WS_TA + c] = rT[0] + rT[1] + rT[2] + rT[3];
      ws[WS_CA + c] += rU[0] + rU[1] + rU[2] + rU[3];
    }
  }
}

// ---------------------------------------------------------------------------
// K3: token kernel. logitA = rstd*(x·PA'' - mu*T_A) + c'A (single raw-x pass).
// Lane split: g = lane>>4 owns d-16th-slice, np = lane&15 owns output n.
// 8 tokens per wave amortize LDS reads. 4 d-quarters staged (33 KB LDS).
// ---------------------------------------------------------------------------
__global__ __launch_bounds__(256) void token_kernel(
    const float* __restrict__ x, const float* __restrict__ ws,
    float* __restrict__ a_buf, float* __restrict__ u_buf) {
  __shared__ float4 lds4[32 * 65];  // 32 rows (PA 0..15, PB 16..31), pad 65
  const int tid = threadIdx.x;
  const int lane = tid & 63;
  const int wv = tid >> 6;
  const int g = lane >> 4;
  const int np = lane & 15;
  const int t0 = blockIdx.x * 32 + wv * 8;

  const float4* __restrict__ x4 = reinterpret_cast<const float4*>(x);
  const float4* __restrict__ ws4 = reinterpret_cast<const float4*>(ws);

  float sum[8], sq[8], SA[8], SB[8];
#pragma unroll
  for (int t = 0; t < 8; ++t) {
    sum[t] = 0.f;
    sq[t] = 0.f;
    SA[t] = 0.f;
    SB[t] = 0.f;
  }

  for (int p = 0; p < 4; ++p) {
    __syncthreads();
#pragma unroll
    for (int i = 0; i < 8; ++i) {
      const int idx = i * 256 + tid;  // 0..2047
      const int r = idx >> 6;
      const int u = idx & 63;
      lds4[r * 65 + u] = ws4[(size_t)r * 256 + p * 64 + u];
    }
    __syncthreads();
    // stats partial (coalesced)
#pragma unroll
    for (int t = 0; t < 8; ++t) {
      const float4 xs = x4[(size_t)(t0 + t) * 256 + p * 64 + lane];
      sum[t] += xs.x + xs.y + xs.z + xs.w;
      sq[t] = fmaf(xs.x, xs.x, sq[t]);
      sq[t] = fmaf(xs.y, xs.y, sq[t]);
      sq[t] = fmaf(xs.z, xs.z, sq[t]);
      sq[t] = fmaf(xs.w, xs.w, sq[t]);
    }
    // projections
#pragma unroll
    for (int j = 0; j < 16; ++j) {
      const float4 pa = lds4[np * 65 + g * 16 + j];
      const float4 pb = lds4[(16 + np) * 65 + g * 16 + j];
#pragma unroll
      for (int t = 0; t < 8; ++t) {
        const float4 xb = x4[(size_t)(t0 + t) * 256 + p * 64 + g * 16 + j];
        SA[t] = fmaf(xb.x, pa.x, SA[t]);
        SA[t] = fmaf(xb.y, pa.y, SA[t]);
        SA[t] = fmaf(xb.z, pa.z, SA[t]);
        SA[t] = fmaf(xb.w, pa.w, SA[t]);
        SB[t] = fmaf(xb.x, pb.x, SB[t]);
        SB[t] = fmaf(xb.y, pb.y, SB[t]);
        SB[t] = fmaf(xb.z, pb.z, SB[t]);
        SB[t] = fmaf(xb.w, pb.w, SB[t]);
      }
    }
  }
  // finish
#pragma unroll
  for (int t = 0; t < 8; ++t) {
    float s = sum[t], q = sq[t];
#pragma unroll
    for (int off = 32; off; off >>= 1) {
      s += __shfl_xor(s, off);
      q += __shfl_xor(q, off);
    }
    const float mu = s * (1.0f / 1024.0f);
    const float var = fmaf(-mu, mu, q * (1.0f / 1024.0f));
    const float rstd = rsqrtf(var + EPS_LN);
    float sa = SA[t] + __shfl_xor(SA[t], 16);
    sa += __shfl_xor(sa, 32);
    float sb = SB[t] + __shfl_xor(SB[t], 16);
    sb += __shfl_xor(sb, 32);
    if (g == 0) {
      const float TA = ws[WS_TA + np];
      const float TB = ws[WS_TB + np];
      const float cA = ws[WS_CA + np];
      const float cB = ws[WS_CB + np];
      const float zA = fmaf(rstd, fmaf(-mu, TA, sa), cA);
      const float zB = fmaf(rstd, fmaf(-mu, TB, sb), cB);
      a_buf[(size_t)(t0 + t) * 16 + np] = 1.0f / (1.0f + __expf(-zA));
      u_buf[(size_t)(t0 + t) * 16 + np] = zB;
    }
  }
}

// ---------------------------------------------------------------------------
// K4-6: 3-phase chunked scan (32 sequences, 64 chunks x 64 steps).
// ---------------------------------------------------------------------------
__global__ __launch_bounds__(256) void scan1_kernel(
    const float* __restrict__ a_buf, const float* __restrict__ u_buf,
    float* __restrict__ carryA, float* __restrict__ carryU) {
  const int task = blockIdx.x * 256 + threadIdx.x;  // 0..2047
  const int seq = task & 31;
  const int chunk = task >> 5;
  const int b = seq >> 4, n = seq & 15;
  const size_t base = ((size_t)b * SEQ + (size_t)chunk * 64) * 16 + n;
  float Ap = 1.f, U = 0.f;
#pragma unroll 8
  for (int i = 0; i < 64; ++i) {
    const float av = a_buf[base + (size_t)i * 16];
    const float uv = u_buf[base + (size_t)i * 16];
    U = fmaf(U, av, uv);
    Ap *= av;
  }
  carryA[task] = Ap;
  carryU[task] = U;
}

__global__ __launch_bounds__(64) void scan2_kernel(
    const float* __restrict__ carryA, const float* __restrict__ carryU,
    float* __restrict__ carryin) {
  const int seq = threadIdx.x;
  if (seq >= 32) return;
  float c = 0.f;
  for (int ch = 0; ch < 64; ++ch) {
    carryin[ch * 32 + seq] = c;
    c = fmaf(c, carryA[ch * 32 + seq], carryU[ch * 32 + seq]);
  }
}

__global__ __launch_bounds__(256) void scan3_kernel(
    const float* __restrict__ a_buf, const float* __restrict__ u_buf,
    const float* __restrict__ carryin, float* __restrict__ states) {
  const int task = blockIdx.x * 256 + threadIdx.x;
  const int seq = task & 31;
  const int chunk = task >> 5;
  const int b = seq >> 4, n = seq & 15;
  const size_t base = ((size_t)b * SEQ + (size_t)chunk * 64) * 16 + n;
  float s = carryin[task];
#pragma unroll 8
  for (int i = 0; i < 64; ++i) {
    const float av = a_buf[base + (size_t)i * 16];
    const float uv = u_buf[base + (size_t)i * 16];
    s = fmaf(s, av, uv);
    states[base + (size_t)i * 16] = s;
  }
}

// ---------------------------------------------------------------------------
// K7: out = states @ M^T + b_out + x. 4 tokens per wave (M^T reads amortized).
// ---------------------------------------------------------------------------
__global__ __launch_bounds__(256) void out_kernel(
    const float* __restrict__ x, const float* __restrict__ ws,
    const float* __restrict__ b_out, float* __restrict__ out) {
  const int tid = threadIdx.x;
  const int lane = tid & 63;
  const int wv = tid >> 6;
  const int t0 = blockIdx.x * 16 + wv * 4;
  const float4* __restrict__ x4 = reinterpret_cast<const float4*>(x);
  const float4* __restrict__ M4 = reinterpret_cast<const float4*>(ws + WS_M);
  const float4* __restrict__ b4 = reinterpret_cast<const float4*>(b_out);
  const float* __restrict__ st = ws + WS_S;
  float4* __restrict__ o4 = reinterpret_cast<float4*>(out);

  float s[4][16];  // wave-uniform -> scalar regs
#pragma unroll
  for (int tt = 0; tt < 4; ++tt)
#pragma unroll
    for (int n = 0; n < 16; ++n) s[tt][n] = st[(size_t)(t0 + tt) * 16 + n];

#pragma unroll
  for (int k = 0; k < 4; ++k) {
    const float4 bv = b4[k * 64 + lane];
    float4 acc[4];
#pragma unroll
    for (int tt = 0; tt < 4; ++tt) {
      const float4 xv = x4[(size_t)(t0 + tt) * 256 + k * 64 + lane];
      acc[tt] =
          make_float4(xv.x + bv.x, xv.y + bv.y, xv.z + bv.z, xv.w + bv.w);
    }
#pragma unroll
    for (int n = 0; n < 16; ++n) {
      const float4 m = M4[(size_t)n * 256 + k * 64 + lane];
#pragma unroll
      for (int tt = 0; tt < 4; ++tt) {
        acc[tt].x = fmaf(s[tt][n], m.x, acc[tt].x);
        acc[tt].y = fmaf(s[tt][n], m.y, acc[tt].y);
        acc[tt].z = fmaf(s[tt][n], m.z, acc[tt].z);
        acc[tt].w = fmaf(s[tt][n], m.w, acc[tt].w);
      }
    }
#pragma unroll
    for (int tt = 0; tt < 4; ++tt)
      o4[(size_t)(t0 + tt) * 256 + k * 64 + lane] = acc[tt];
  }
}

// ---------------------------------------------------------------------------
extern "C" void kernel_launch(void* const* d_in, const int* in_sizes, int n_in,
                              void* d_out, int out_size, void* d_ws,
                              size_t ws_size, hipStream_t stream) {
  const float* x = (const float*)d_in[0];
  const float* norm_w = (const float*)d_in[1];
  const float* norm_b = (const float*)d_in[2];
  const float* W_in = (const float*)d_in[3];
  const float* b_in = (const float*)d_in[4];
  const float* A = (const float*)d_in[5];
  const float* B_ssm = (const float*)d_in[6];
  const float* C_ssm = (const float*)d_in[7];
  const float* W_out = (const float*)d_in[8];
  const float* b_out = (const float*)d_in[9];
  float* ws = (float*)d_ws;
  float* out = (float*)d_out;

  precompute_kernel<<<194, 256, 0, stream>>>(W_in, b_in, A, B_ssm, C_ssm,
                                             W_out, ws);
  reduce_kernel<<<160, 256, 0, stream>>>(norm_w, norm_b, ws);
  token_kernel<<<256, 256, 0, stream>>>(x, ws, ws + WS_A, ws + WS_U);
  scan1_kernel<<<8, 256, 0, stream>>>(ws + WS_A, ws + WS_U, ws + WS_CARRYA,
                                      ws + WS_CARRYU);
  scan2_kernel<<<1, 64, 0, stream>>>(ws + WS_CARRYA, ws + WS_CARRYU,
                                     ws + WS_CARRYIN);
  scan3_kernel<<<8, 256, 0, stream>>>(ws + WS_A, ws + WS_U, ws + WS_CARRYIN,
                                      ws + WS_S);
  out_kernel<<<512, 256, 0, stream>>>(x, ws, b_out, out);
}